// Round 1
// baseline (231.080 us; speedup 1.0000x reference)
//
#include <hip/hip_runtime.h>
#include <hip/hip_bf16.h>

#define BATCH  4096
#define UNITS  1024
#define CDIM   2048   // K = UNITS + IN_DIM
#define NDIM   4096   // 4 * UNITS (f, i, c, o)

typedef __attribute__((ext_vector_type(8))) short bf16x8;
typedef __attribute__((ext_vector_type(4))) float f32x4;

__device__ __forceinline__ void gload_lds16(const void* g, void* l) {
    __builtin_amdgcn_global_load_lds(
        (const __attribute__((address_space(1))) unsigned int*)g,
        (__attribute__((address_space(3))) unsigned int*)l, 16, 0, 0);
}

__device__ __forceinline__ float sigm(float x) { return 1.f / (1.f + __expf(-x)); }
__device__ __forceinline__ float tanh_fast(float x) { return 2.f / (1.f + __expf(-2.f * x)) - 1.f; }

__device__ __forceinline__ short f2bf(float f) {
    __hip_bfloat16 h = __float2bfloat16(f);
    return *reinterpret_cast<short*>(&h);
}

// ---- prep v2: fully vectorized, no LDS ---------------------------------------
// Wt row layout (gate-interleaved, 128-periodic):
//   n(u,g) = (u>>5)*128 + ((u>>4)&1)*64 + g*16 + (u&15)
//
// Blocks [0, 4096):    concat-cast x. Thread = 8 consecutive elements:
//                      2x float4 load -> 1x 16B bf16x8 store.
// Blocks [4096, 5120): transpose-cast W. Block = one gate, 64u x 128k region.
//                      Register transpose: lane owns one u; 32 coalesced
//                      column-loads (64 lanes x 4B = 256B/instr) accumulate
//                      32 consecutive k in VGPRs -> 4x 16B bf16x8 stores,
//                      K-contiguous in Wt. Each block writes 256B runs per
//                      output row -> full 128B-line coverage (no partial-line
//                      writebacks, unlike the old 32x32-tile version).
__global__ __launch_bounds__(256) void prep(
        const float* __restrict__ h, const float* __restrict__ in,
        const float* __restrict__ Wf, const float* __restrict__ Wi,
        const float* __restrict__ Wc, const float* __restrict__ Wo,
        __hip_bfloat16* __restrict__ x, __hip_bfloat16* __restrict__ Wt) {
    int b = blockIdx.x, tid = threadIdx.x;
    if (b < 4096) {
        // concat(hidden, inputs) -> bf16 x [BATCH, CDIM]
        int t   = b * 256 + tid;          // 1M threads, 8 elems each
        int row = t >> 8;                 // CDIM/8 = 256 chunks per row
        int c8  = (t & 255) << 3;
        const float* src = (c8 < UNITS) ? (h + (size_t)row * UNITS + c8)
                                        : (in + (size_t)row * UNITS + (c8 - UNITS));
        float4 v0 = ((const float4*)src)[0];
        float4 v1 = ((const float4*)src)[1];
        bf16x8 o;
        o[0] = f2bf(v0.x); o[1] = f2bf(v0.y); o[2] = f2bf(v0.z); o[3] = f2bf(v0.w);
        o[4] = f2bf(v1.x); o[5] = f2bf(v1.y); o[6] = f2bf(v1.z); o[7] = f2bf(v1.w);
        *(bf16x8*)(x + (size_t)row * CDIM + c8) = o;
    } else {
        // transpose-cast W_g[CDIM, UNITS] -> permuted Wt[NDIM, CDIM]
        int idx = b - 4096;               // 1024 blocks = g(4) x ut(16) x kt(16)
        int g = idx >> 8, ut = (idx >> 4) & 15, kt = idx & 15;
        const float* W = (g == 0) ? Wf : (g == 1) ? Wi : (g == 2) ? Wc : Wo;
        int w = tid >> 6, l = tid & 63;   // wave w covers 32 k, lane l owns u
        int u  = ut * 64 + l;
        int k0 = kt * 128 + w * 32;
        int n  = ((u >> 5) << 7) + (((u >> 4) & 1) << 6) + (g << 4) + (u & 15);
        const float* Wp = W + (size_t)k0 * UNITS + u;
        __hip_bfloat16* dst = Wt + (size_t)n * CDIM + k0;
        float v[32];
#pragma unroll
        for (int j = 0; j < 32; ++j) v[j] = Wp[(size_t)j * UNITS];
#pragma unroll
        for (int q = 0; q < 4; ++q) {
            bf16x8 o;
#pragma unroll
            for (int e = 0; e < 8; ++e) o[e] = f2bf(v[q * 8 + e]);
            *(bf16x8*)(dst + q * 8) = o;
        }
    }
}

// ---- flatmm-style fused GEMM + LSTM gates -----------------------------------
// Block 128m x 256n, 256 threads = 4 waves; wave = 128m x 64n (8i x 4j MFMA).
// A staged via global_load_lds (BK=64, r2-proven xor8 swizzle, double-buffered);
// B streamed L2 -> VGPR with 1-deep register prefetch (no LDS, no barrier dep).
// 512 blocks = 2/CU for inter-block TLP. Fused LSTM epilogue.
__global__ __launch_bounds__(256, 2) void gemm_lstm(
    const __hip_bfloat16* __restrict__ A,    // [BATCH, CDIM] bf16
    const __hip_bfloat16* __restrict__ Bt,   // [NDIM, CDIM] bf16, gate-interleaved
    const float* __restrict__ b_f, const float* __restrict__ b_i,
    const float* __restrict__ b_c, const float* __restrict__ b_o,
    const float* __restrict__ cell,          // [BATCH, UNITS]
    float* __restrict__ out)                 // [2, BATCH, UNITS]: hidden, cell
{
    __shared__ short As[2][128 * 64];        // 2 x 16 KB, rows of 128 B
    const int K = CDIM;

    // XCD swizzle: xcd = bid&7 gets n-slice of 512 (2 nb) -> B slice 2 MB, L2-resident
    int bid = blockIdx.x;
    int nb  = (bid & 7) * 2 + ((bid >> 3) & 1);
    int mb  = bid >> 4;
    int m0  = mb * 128, n0 = nb * 256;

    int tid  = threadIdx.x;
    int w    = tid >> 6, lane = tid & 63;
    int quad = lane >> 4, r16 = lane & 15;
    int wn   = w * 64;

    f32x4 acc[8][4];
#pragma unroll
    for (int i = 0; i < 8; ++i)
#pragma unroll
        for (int j = 0; j < 4; ++j) acc[i][j] = (f32x4){0.f, 0.f, 0.f, 0.f};

    const short* Ag = (const short*)A  + (size_t)m0 * K;
    // per-lane B base: row n0+wn+j*16+r16, chunk quad
    const short* Bg = (const short*)Bt + (size_t)(n0 + wn + r16) * K + quad * 8;

    auto stageA = [&](int p, int k0) {
#pragma unroll
        for (int q = 0; q < 4; ++q) {
            int s    = q * 256 + tid;          // 1024 slots of 16B = 128 rows x 128B
            int row  = s >> 3;
            int cg   = (s & 7) ^ (row & 7);    // swizzled global chunk (r2-proven)
            int lofs = (q * 256 + w * 64) * 8; // wave-uniform LDS base (shorts)
            gload_lds16(Ag + (size_t)row * K + k0 + cg * 8, &As[p][lofs]);
        }
    };

    bf16x8 bcur[8], bnxt[8];
#pragma unroll
    for (int ks = 0; ks < 2; ++ks)
#pragma unroll
        for (int j = 0; j < 4; ++j)
            bcur[ks * 4 + j] = *(const bf16x8*)&Bg[(size_t)(j * 16) * K + ks * 32];
    stageA(0, 0);

    for (int kt = 0; kt < K / 64; ++kt) {
        int p = kt & 1;
        asm volatile("s_waitcnt vmcnt(0)" ::: "memory");  // A(kt) in LDS, B(kt) in regs
        __syncthreads();
        if (kt + 1 < K / 64) {
            stageA(1 - p, (kt + 1) * 64);                 // overlap compute below
            int kb = (kt + 1) * 64;
#pragma unroll
            for (int ks = 0; ks < 2; ++ks)
#pragma unroll
                for (int j = 0; j < 4; ++j)
                    bnxt[ks * 4 + j] = *(const bf16x8*)&Bg[(size_t)(j * 16) * K + kb + ks * 32];
        }
#pragma unroll
        for (int ks = 0; ks < 2; ++ks) {
            bf16x8 af[8];
            int kc = ((quad + ks * 4) ^ (r16 & 7)) * 8;
#pragma unroll
            for (int i = 0; i < 8; ++i)
                af[i] = *(const bf16x8*)&As[p][(i * 16 + r16) * 64 + kc];
#pragma unroll
            for (int i = 0; i < 8; ++i)
#pragma unroll
                for (int j = 0; j < 4; ++j)
                    acc[i][j] = __builtin_amdgcn_mfma_f32_16x16x32_bf16(af[i], bcur[ks * 4 + j], acc[i][j], 0, 0, 0);
        }
#pragma unroll
        for (int t = 0; t < 8; ++t) bcur[t] = bnxt[t];
    }

    // ---- fused LSTM epilogue: j = gate, u = nb*64 + (w>>1)*32 + (w&1)*16 + r16
    // C/D layout: col=lane&15, row=quad*4+reg (m89-verified)
    int u = nb * 64 + (w >> 1) * 32 + (w & 1) * 16 + r16;
    float bfv = b_f[u], biv = b_i[u], bcv = b_c[u], bov = b_o[u];
    float* out_h = out;
    float* out_c = out + (size_t)BATCH * UNITS;
#pragma unroll
    for (int i = 0; i < 8; ++i) {
#pragma unroll
        for (int rr = 0; rr < 4; ++rr) {
            int m = m0 + i * 16 + quad * 4 + rr;
            float fg = sigm(acc[i][0][rr] + bfv);
            float ig = sigm(acc[i][1][rr] + biv);
            float cc = tanh_fast(acc[i][2][rr] + bcv);
            float og = sigm(acc[i][3][rr] + bov);
            float cold = cell[(size_t)m * UNITS + u];
            float cn = fg * cold + ig * cc;
            out_h[(size_t)m * UNITS + u] = og * tanh_fast(cn);
            out_c[(size_t)m * UNITS + u] = cn;
        }
    }
}

extern "C" void kernel_launch(void* const* d_in, const int* in_sizes, int n_in,
                              void* d_out, int out_size, void* d_ws, size_t ws_size,
                              hipStream_t stream) {
    const float* inputs = (const float*)d_in[0];
    const float* hidden = (const float*)d_in[1];
    const float* cell   = (const float*)d_in[2];
    const float* Wf = (const float*)d_in[3];
    const float* bf_ = (const float*)d_in[4];
    const float* Wi = (const float*)d_in[5];
    const float* bi_ = (const float*)d_in[6];
    const float* Wc = (const float*)d_in[7];
    const float* bc_ = (const float*)d_in[8];
    const float* Wo = (const float*)d_in[9];
    const float* bo_ = (const float*)d_in[10];
    float* out = (float*)d_out;

    char* ws = (char*)d_ws;
    __hip_bfloat16* x  = (__hip_bfloat16*)ws;                  // 16 MB
    __hip_bfloat16* Wt = (__hip_bfloat16*)(ws + (16u << 20));  // 16 MB

    // 1) concat-cast x (4096 blocks) + register-transpose-cast W (1024 blocks)
    prep<<<dim3(5120), dim3(256), 0, stream>>>(hidden, inputs, Wf, Wi, Wc, Wo, x, Wt);
    // 2) flatmm-style fused 4-gate GEMM + LSTM gates (512 blocks = 2/CU)
    gemm_lstm<<<dim3(512), dim3(256), 0, stream>>>(
        x, Wt, bf_, bi_, bc_, bo_, cell, out);
}

// Round 2
// 219.338 us; speedup vs baseline: 1.0535x; 1.0535x over previous
//
#include <hip/hip_runtime.h>
#include <hip/hip_bf16.h>

#define BATCH  4096
#define UNITS  1024
#define CDIM   2048   // K = UNITS + IN_DIM
#define NDIM   4096   // 4 * UNITS (f, i, c, o)

typedef __attribute__((ext_vector_type(8))) short bf16x8;
typedef __attribute__((ext_vector_type(4))) short bf16x4;
typedef __attribute__((ext_vector_type(4))) float f32x4;

__device__ __forceinline__ void gload_lds16(const void* g, void* l) {
    __builtin_amdgcn_global_load_lds(
        (const __attribute__((address_space(1))) unsigned int*)g,
        (__attribute__((address_space(3))) unsigned int*)l, 16, 0, 0);
}

__device__ __forceinline__ float sigm(float x) { return 1.f / (1.f + __expf(-x)); }
__device__ __forceinline__ float tanh_fast(float x) { return 2.f / (1.f + __expf(-2.f * x)) - 1.f; }

__device__ __forceinline__ short f2bf(float f) {
    __hip_bfloat16 h = __float2bfloat16(f);
    return *reinterpret_cast<short*>(&h);
}

// ---- prep v3 -----------------------------------------------------------------
// Wt row layout (gate-interleaved, 128-periodic):
//   n(u,g) = (u>>5)*128 + ((u>>4)&1)*64 + g*16 + (u&15)
//
// Blocks [0, 4096):    concat-cast x. Thread = 8 consecutive elements:
//                      2x float4 load -> 1x 16B bf16x8 store. (proven pattern)
// Blocks [4096, 6144): transpose-cast W via LDS, 64k x 64u tile per block.
//   Phase 1: float4 loads (wave-instr = 4 rows x 256B runs, coalesced)
//            -> LDS [64][65] f32 (stride-65 scalar writes, ~2-way = free).
//   Phase 2: lane packs 4 k-consecutive f32 -> bf16x4 (8B) store.
//            Wave-instr = 4 consecutive n-rows x 16 lanes x 8B
//            = 4 FULL 128B lines per instruction. No partial-line writebacks,
//            no 64-line scatter (v2's failure mode).
__global__ __launch_bounds__(256) void prep(
        const float* __restrict__ h, const float* __restrict__ in,
        const float* __restrict__ Wf, const float* __restrict__ Wi,
        const float* __restrict__ Wc, const float* __restrict__ Wo,
        __hip_bfloat16* __restrict__ x, __hip_bfloat16* __restrict__ Wt) {
    __shared__ float lds[64 * 65];
    int b = blockIdx.x, tid = threadIdx.x;
    if (b < 4096) {
        // concat(hidden, inputs) -> bf16 x [BATCH, CDIM]
        int t   = b * 256 + tid;          // 1M threads, 8 elems each
        int row = t >> 8;                 // CDIM/8 = 256 chunks per row
        int c8  = (t & 255) << 3;
        const float* src = (c8 < UNITS) ? (h + (size_t)row * UNITS + c8)
                                        : (in + (size_t)row * UNITS + (c8 - UNITS));
        float4 v0 = ((const float4*)src)[0];
        float4 v1 = ((const float4*)src)[1];
        bf16x8 o;
        o[0] = f2bf(v0.x); o[1] = f2bf(v0.y); o[2] = f2bf(v0.z); o[3] = f2bf(v0.w);
        o[4] = f2bf(v1.x); o[5] = f2bf(v1.y); o[6] = f2bf(v1.z); o[7] = f2bf(v1.w);
        *(bf16x8*)(x + (size_t)row * CDIM + c8) = o;
    } else {
        // transpose-cast W_g[CDIM, UNITS] -> permuted Wt[NDIM, CDIM]
        int idx = b - 4096;               // 2048 blocks = g(4) x kt(32) x ut(16)
        int g = idx >> 9, kt = (idx >> 4) & 31, ut = idx & 15;
        const float* W = (g == 0) ? Wf : (g == 1) ? Wi : (g == 2) ? Wc : Wo;
        int k0 = kt * 64, u0 = ut * 64;
        int r16 = tid & 15, hi = tid >> 4;   // hi = w*4 + quad
        // Phase 1: read 64x64 f32 tile, coalesced along u
#pragma unroll
        for (int it = 0; it < 4; ++it) {
            int kl = it * 16 + hi;
            float4 v = *(const float4*)&W[(size_t)(k0 + kl) * UNITS + u0 + r16 * 4];
            float* d = &lds[kl * 65 + r16 * 4];
            d[0] = v.x; d[1] = v.y; d[2] = v.z; d[3] = v.w;
        }
        __syncthreads();
        // Phase 2: write k-contiguous bf16x4 runs, full-line wave stores
#pragma unroll
        for (int it = 0; it < 4; ++it) {
            int ul = it * 16 + hi;
            int u  = u0 + ul;
            int n  = ((u >> 5) << 7) + (((u >> 4) & 1) << 6) + (g << 4) + (u & 15);
            bf16x4 o;
#pragma unroll
            for (int j = 0; j < 4; ++j) o[j] = f2bf(lds[(r16 * 4 + j) * 65 + ul]);
            *(bf16x4*)(Wt + (size_t)n * CDIM + k0 + r16 * 4) = o;
        }
    }
}

// ---- flatmm-style fused GEMM + LSTM gates (FROZEN this round: control) ------
// Block 128m x 256n, 256 threads = 4 waves; wave = 128m x 64n (8i x 4j MFMA).
// A staged via global_load_lds (BK=64, r2-proven xor8 swizzle, double-buffered);
// B streamed L2 -> VGPR with 1-deep register prefetch (no LDS, no barrier dep).
// 512 blocks = 2/CU for inter-block TLP. Fused LSTM epilogue.
__global__ __launch_bounds__(256, 2) void gemm_lstm(
    const __hip_bfloat16* __restrict__ A,    // [BATCH, CDIM] bf16
    const __hip_bfloat16* __restrict__ Bt,   // [NDIM, CDIM] bf16, gate-interleaved
    const float* __restrict__ b_f, const float* __restrict__ b_i,
    const float* __restrict__ b_c, const float* __restrict__ b_o,
    const float* __restrict__ cell,          // [BATCH, UNITS]
    float* __restrict__ out)                 // [2, BATCH, UNITS]: hidden, cell
{
    __shared__ short As[2][128 * 64];        // 2 x 16 KB, rows of 128 B
    const int K = CDIM;

    // XCD swizzle: xcd = bid&7 gets n-slice of 512 (2 nb) -> B slice 2 MB, L2-resident
    int bid = blockIdx.x;
    int nb  = (bid & 7) * 2 + ((bid >> 3) & 1);
    int mb  = bid >> 4;
    int m0  = mb * 128, n0 = nb * 256;

    int tid  = threadIdx.x;
    int w    = tid >> 6, lane = tid & 63;
    int quad = lane >> 4, r16 = lane & 15;
    int wn   = w * 64;

    f32x4 acc[8][4];
#pragma unroll
    for (int i = 0; i < 8; ++i)
#pragma unroll
        for (int j = 0; j < 4; ++j) acc[i][j] = (f32x4){0.f, 0.f, 0.f, 0.f};

    const short* Ag = (const short*)A  + (size_t)m0 * K;
    // per-lane B base: row n0+wn+j*16+r16, chunk quad
    const short* Bg = (const short*)Bt + (size_t)(n0 + wn + r16) * K + quad * 8;

    auto stageA = [&](int p, int k0) {
#pragma unroll
        for (int q = 0; q < 4; ++q) {
            int s    = q * 256 + tid;          // 1024 slots of 16B = 128 rows x 128B
            int row  = s >> 3;
            int cg   = (s & 7) ^ (row & 7);    // swizzled global chunk (r2-proven)
            int lofs = (q * 256 + w * 64) * 8; // wave-uniform LDS base (shorts)
            gload_lds16(Ag + (size_t)row * K + k0 + cg * 8, &As[p][lofs]);
        }
    };

    bf16x8 bcur[8], bnxt[8];
#pragma unroll
    for (int ks = 0; ks < 2; ++ks)
#pragma unroll
        for (int j = 0; j < 4; ++j)
            bcur[ks * 4 + j] = *(const bf16x8*)&Bg[(size_t)(j * 16) * K + ks * 32];
    stageA(0, 0);

    for (int kt = 0; kt < K / 64; ++kt) {
        int p = kt & 1;
        asm volatile("s_waitcnt vmcnt(0)" ::: "memory");  // A(kt) in LDS, B(kt) in regs
        __syncthreads();
        if (kt + 1 < K / 64) {
            stageA(1 - p, (kt + 1) * 64);                 // overlap compute below
            int kb = (kt + 1) * 64;
#pragma unroll
            for (int ks = 0; ks < 2; ++ks)
#pragma unroll
                for (int j = 0; j < 4; ++j)
                    bnxt[ks * 4 + j] = *(const bf16x8*)&Bg[(size_t)(j * 16) * K + kb + ks * 32];
        }
#pragma unroll
        for (int ks = 0; ks < 2; ++ks) {
            bf16x8 af[8];
            int kc = ((quad + ks * 4) ^ (r16 & 7)) * 8;
#pragma unroll
            for (int i = 0; i < 8; ++i)
                af[i] = *(const bf16x8*)&As[p][(i * 16 + r16) * 64 + kc];
#pragma unroll
            for (int i = 0; i < 8; ++i)
#pragma unroll
                for (int j = 0; j < 4; ++j)
                    acc[i][j] = __builtin_amdgcn_mfma_f32_16x16x32_bf16(af[i], bcur[ks * 4 + j], acc[i][j], 0, 0, 0);
        }
#pragma unroll
        for (int t = 0; t < 8; ++t) bcur[t] = bnxt[t];
    }

    // ---- fused LSTM epilogue: j = gate, u = nb*64 + (w>>1)*32 + (w&1)*16 + r16
    // C/D layout: col=lane&15, row=quad*4+reg (m89-verified)
    int u = nb * 64 + (w >> 1) * 32 + (w & 1) * 16 + r16;
    float bfv = b_f[u], biv = b_i[u], bcv = b_c[u], bov = b_o[u];
    float* out_h = out;
    float* out_c = out + (size_t)BATCH * UNITS;
#pragma unroll
    for (int i = 0; i < 8; ++i) {
#pragma unroll
        for (int rr = 0; rr < 4; ++rr) {
            int m = m0 + i * 16 + quad * 4 + rr;
            float fg = sigm(acc[i][0][rr] + bfv);
            float ig = sigm(acc[i][1][rr] + biv);
            float cc = tanh_fast(acc[i][2][rr] + bcv);
            float og = sigm(acc[i][3][rr] + bov);
            float cold = cell[(size_t)m * UNITS + u];
            float cn = fg * cold + ig * cc;
            out_h[(size_t)m * UNITS + u] = og * tanh_fast(cn);
            out_c[(size_t)m * UNITS + u] = cn;
        }
    }
}

extern "C" void kernel_launch(void* const* d_in, const int* in_sizes, int n_in,
                              void* d_out, int out_size, void* d_ws, size_t ws_size,
                              hipStream_t stream) {
    const float* inputs = (const float*)d_in[0];
    const float* hidden = (const float*)d_in[1];
    const float* cell   = (const float*)d_in[2];
    const float* Wf = (const float*)d_in[3];
    const float* bf_ = (const float*)d_in[4];
    const float* Wi = (const float*)d_in[5];
    const float* bi_ = (const float*)d_in[6];
    const float* Wc = (const float*)d_in[7];
    const float* bc_ = (const float*)d_in[8];
    const float* Wo = (const float*)d_in[9];
    const float* bo_ = (const float*)d_in[10];
    float* out = (float*)d_out;

    char* ws = (char*)d_ws;
    __hip_bfloat16* x  = (__hip_bfloat16*)ws;                  // 16 MB
    __hip_bfloat16* Wt = (__hip_bfloat16*)(ws + (16u << 20));  // 16 MB

    // 1) concat-cast x (4096 blocks) + LDS-transpose-cast W (2048 blocks)
    prep<<<dim3(6144), dim3(256), 0, stream>>>(hidden, inputs, Wf, Wi, Wc, Wo, x, Wt);
    // 2) flatmm-style fused 4-gate GEMM + LSTM gates (512 blocks = 2/CU)
    gemm_lstm<<<dim3(512), dim3(256), 0, stream>>>(
        x, Wt, bf_, bi_, bc_, bo_, cell, out);
}

// Round 3
// 211.831 us; speedup vs baseline: 1.0909x; 1.0354x over previous
//
#include <hip/hip_runtime.h>
#include <hip/hip_bf16.h>

#define BATCH  4096
#define UNITS  1024
#define CDIM   2048   // K = UNITS + IN_DIM
#define NDIM   4096   // 4 * UNITS (f, i, c, o)

typedef __attribute__((ext_vector_type(8))) short bf16x8;
typedef __attribute__((ext_vector_type(4))) short bf16x4;
typedef __attribute__((ext_vector_type(4))) float f32x4;

__device__ __forceinline__ void gload_lds16(const void* g, void* l) {
    __builtin_amdgcn_global_load_lds(
        (const __attribute__((address_space(1))) unsigned int*)g,
        (__attribute__((address_space(3))) unsigned int*)l, 16, 0, 0);
}

__device__ __forceinline__ float sigm(float x) { return 1.f / (1.f + __expf(-x)); }
__device__ __forceinline__ float tanh_fast(float x) { return 2.f / (1.f + __expf(-2.f * x)) - 1.f; }

__device__ __forceinline__ short f2bf(float f) {
    __hip_bfloat16 h = __float2bfloat16(f);
    return *reinterpret_cast<short*>(&h);
}

// ---- prep v3 (FROZEN control: ~30 us, near 128 MB roofline) -----------------
// Wt row layout (gate-interleaved, 128-periodic):
//   n(u,g) = (u>>5)*128 + ((u>>4)&1)*64 + g*16 + (u&15)
__global__ __launch_bounds__(256) void prep(
        const float* __restrict__ h, const float* __restrict__ in,
        const float* __restrict__ Wf, const float* __restrict__ Wi,
        const float* __restrict__ Wc, const float* __restrict__ Wo,
        __hip_bfloat16* __restrict__ x, __hip_bfloat16* __restrict__ Wt) {
    __shared__ float lds[64 * 65];
    int b = blockIdx.x, tid = threadIdx.x;
    if (b < 4096) {
        // concat(hidden, inputs) -> bf16 x [BATCH, CDIM]
        int t   = b * 256 + tid;
        int row = t >> 8;
        int c8  = (t & 255) << 3;
        const float* src = (c8 < UNITS) ? (h + (size_t)row * UNITS + c8)
                                        : (in + (size_t)row * UNITS + (c8 - UNITS));
        float4 v0 = ((const float4*)src)[0];
        float4 v1 = ((const float4*)src)[1];
        bf16x8 o;
        o[0] = f2bf(v0.x); o[1] = f2bf(v0.y); o[2] = f2bf(v0.z); o[3] = f2bf(v0.w);
        o[4] = f2bf(v1.x); o[5] = f2bf(v1.y); o[6] = f2bf(v1.z); o[7] = f2bf(v1.w);
        *(bf16x8*)(x + (size_t)row * CDIM + c8) = o;
    } else {
        // transpose-cast W_g[CDIM, UNITS] -> permuted Wt[NDIM, CDIM]
        int idx = b - 4096;               // 2048 blocks = g(4) x kt(32) x ut(16)
        int g = idx >> 9, kt = (idx >> 4) & 31, ut = idx & 15;
        const float* W = (g == 0) ? Wf : (g == 1) ? Wi : (g == 2) ? Wc : Wo;
        int k0 = kt * 64, u0 = ut * 64;
        int r16 = tid & 15, hi = tid >> 4;
#pragma unroll
        for (int it = 0; it < 4; ++it) {
            int kl = it * 16 + hi;
            float4 v = *(const float4*)&W[(size_t)(k0 + kl) * UNITS + u0 + r16 * 4];
            float* d = &lds[kl * 65 + r16 * 4];
            d[0] = v.x; d[1] = v.y; d[2] = v.z; d[3] = v.w;
        }
        __syncthreads();
#pragma unroll
        for (int it = 0; it < 4; ++it) {
            int ul = it * 16 + hi;
            int u  = u0 + ul;
            int n  = ((u >> 5) << 7) + (((u >> 4) & 1) << 6) + (g << 4) + (u & 15);
            bf16x4 o;
#pragma unroll
            for (int j = 0; j < 4; ++j) o[j] = f2bf(lds[(r16 * 4 + j) * 65 + ul]);
            *(bf16x4*)(Wt + (size_t)n * CDIM + k0 + r16 * 4) = o;
        }
    }
}

// ---- gemm v2: 3-deep counted-vmcnt pipeline (T3+T4+T5) ----------------------
// Block 128m x 256n, 256 threads = 4 waves; wave = 128m x 64n (8i x 4j MFMA).
// BK=32; A(8KB) + B(16KB) both staged via global_load_lds into a 3-deep
// circular LDS buffer (72 KB total -> still 2 blocks/CU; VGPR ~96+128acc).
// Steady state: ONE raw s_barrier per K-step, s_waitcnt vmcnt(6) (one full
// stage of 6 loads/thread stays in flight across the barrier; never drain
// to 0 until the last step). Both-sides XOR swizzle chunk^(row&3) keeps
// ds_read_b128 ~conflict-free. setprio(1) around the MFMA cluster.
// Race check: stage at iter t writes buf[(t+2)%3] = buf[(t-1)%3]; all waves
// consumed buf[(t-1)%3] via MFMAs (which forced lgkmcnt on their ds_reads)
// BEFORE reaching barrier(t), so the overwrite is ordered. Reads of
// buf[t%3] are covered by vmcnt(6)-wait(t) + barrier(t): its 6 loads were
// issued at iter t-2 and are the oldest outstanding.
__global__ __launch_bounds__(256, 2) void gemm_lstm(
    const __hip_bfloat16* __restrict__ A,    // [BATCH, CDIM] bf16
    const __hip_bfloat16* __restrict__ Bt,   // [NDIM, CDIM] bf16, gate-interleaved
    const float* __restrict__ b_f, const float* __restrict__ b_i,
    const float* __restrict__ b_c, const float* __restrict__ b_o,
    const float* __restrict__ cell,          // [BATCH, UNITS]
    float* __restrict__ out)                 // [2, BATCH, UNITS]: hidden, cell
{
    __shared__ alignas(16) short As[3][128 * 32];   // 3 x 8 KB
    __shared__ alignas(16) short Bs[3][256 * 32];   // 3 x 16 KB
    const int K = CDIM;
    const int NT = K / 32;                   // 64 K-steps

    // XCD swizzle: xcd = bid&7 gets n-slice of 512 (2 nb) -> B slice L2-resident
    int bid = blockIdx.x;
    int nb  = (bid & 7) * 2 + ((bid >> 3) & 1);
    int mb  = bid >> 4;
    int m0  = mb * 128, n0 = nb * 256;

    int tid  = threadIdx.x;
    int w    = tid >> 6, lane = tid & 63;
    int quad = lane >> 4, r16 = lane & 15;
    int wn   = w * 64;

    f32x4 acc[8][4];
#pragma unroll
    for (int i = 0; i < 8; ++i)
#pragma unroll
        for (int j = 0; j < 4; ++j) acc[i][j] = (f32x4){0.f, 0.f, 0.f, 0.f};

    const short* Ag = (const short*)A  + (size_t)m0 * K;
    const short* Bg = (const short*)Bt + (size_t)n0 * K;

    // stage one K-step: A 512 slots (2/thread) + B 1024 slots (4/thread) = 6 VMEM
    auto stage = [&](short* Al, short* Bl, int kt) {
        int k0 = kt * 32;
#pragma unroll
        for (int q = 0; q < 2; ++q) {
            int s = q * 256 + tid;             // slot: 4 slots (64B) per row
            int row = s >> 2, c = (s & 3) ^ (row & 3);   // inverse-swz source
            gload_lds16(Ag + (size_t)row * K + k0 + c * 8, Al + (q * 256 + wn) * 8);
        }
#pragma unroll
        for (int q = 0; q < 4; ++q) {
            int s = q * 256 + tid;
            int n = s >> 2, c = (s & 3) ^ (n & 3);
            gload_lds16(Bg + (size_t)n * K + k0 + c * 8, Bl + (q * 256 + wn) * 8);
        }
    };

    short *a0 = &As[0][0], *a1 = &As[1][0], *a2 = &As[2][0];
    short *b0 = &Bs[0][0], *b1 = &Bs[1][0], *b2 = &Bs[2][0];
    stage(a0, b0, 0);
    stage(a1, b1, 1);

    for (int t = 0; t < NT; ++t) {
        if (t < NT - 1) asm volatile("s_waitcnt vmcnt(6)" ::: "memory");
        else            asm volatile("s_waitcnt vmcnt(0)" ::: "memory");
        __builtin_amdgcn_s_barrier();        // raw: no compiler vmcnt(0) drain
        if (t + 2 < NT) stage(a2, b2, t + 2);

        int kc = (quad ^ (r16 & 3)) * 8;     // swizzled read chunk (matches source swz)
        bf16x8 af[8], bf[4];
#pragma unroll
        for (int i = 0; i < 8; ++i)
            af[i] = *(const bf16x8*)&a0[(i * 16 + r16) * 32 + kc];
#pragma unroll
        for (int j = 0; j < 4; ++j)
            bf[j] = *(const bf16x8*)&b0[(wn + j * 16 + r16) * 32 + kc];

        __builtin_amdgcn_s_setprio(1);
#pragma unroll
        for (int i = 0; i < 8; ++i)
#pragma unroll
            for (int j = 0; j < 4; ++j)
                acc[i][j] = __builtin_amdgcn_mfma_f32_16x16x32_bf16(af[i], bf[j], acc[i][j], 0, 0, 0);
        __builtin_amdgcn_s_setprio(0);

        short* ta = a0; a0 = a1; a1 = a2; a2 = ta;
        short* tb = b0; b0 = b1; b1 = b2; b2 = tb;
    }

    // ---- fused LSTM epilogue: j = gate, u = nb*64 + (w>>1)*32 + (w&1)*16 + r16
    // C/D layout: col=lane&15, row=quad*4+reg (m89-verified)
    int u = nb * 64 + (w >> 1) * 32 + (w & 1) * 16 + r16;
    float bfv = b_f[u], biv = b_i[u], bcv = b_c[u], bov = b_o[u];
    float* out_h = out;
    float* out_c = out + (size_t)BATCH * UNITS;
#pragma unroll
    for (int i = 0; i < 8; ++i) {
#pragma unroll
        for (int rr = 0; rr < 4; ++rr) {
            int m = m0 + i * 16 + quad * 4 + rr;
            float fg = sigm(acc[i][0][rr] + bfv);
            float ig = sigm(acc[i][1][rr] + biv);
            float cc = tanh_fast(acc[i][2][rr] + bcv);
            float og = sigm(acc[i][3][rr] + bov);
            float cold = cell[(size_t)m * UNITS + u];
            float cn = fg * cold + ig * cc;
            out_h[(size_t)m * UNITS + u] = og * tanh_fast(cn);
            out_c[(size_t)m * UNITS + u] = cn;
        }
    }
}

extern "C" void kernel_launch(void* const* d_in, const int* in_sizes, int n_in,
                              void* d_out, int out_size, void* d_ws, size_t ws_size,
                              hipStream_t stream) {
    const float* inputs = (const float*)d_in[0];
    const float* hidden = (const float*)d_in[1];
    const float* cell   = (const float*)d_in[2];
    const float* Wf = (const float*)d_in[3];
    const float* bf_ = (const float*)d_in[4];
    const float* Wi = (const float*)d_in[5];
    const float* bi_ = (const float*)d_in[6];
    const float* Wc = (const float*)d_in[7];
    const float* bc_ = (const float*)d_in[8];
    const float* Wo = (const float*)d_in[9];
    const float* bo_ = (const float*)d_in[10];
    float* out = (float*)d_out;

    char* ws = (char*)d_ws;
    __hip_bfloat16* x  = (__hip_bfloat16*)ws;                  // 16 MB
    __hip_bfloat16* Wt = (__hip_bfloat16*)(ws + (16u << 20));  // 16 MB

    // 1) concat-cast x (4096 blocks) + LDS-transpose-cast W (2048 blocks)
    prep<<<dim3(6144), dim3(256), 0, stream>>>(hidden, inputs, Wf, Wi, Wc, Wo, x, Wt);
    // 2) deep-pipelined fused 4-gate GEMM + LSTM gates (512 blocks = 2/CU)
    gemm_lstm<<<dim3(512), dim3(256), 0, stream>>>(
        x, Wt, bf_, bi_, bc_, bo_, cell, out);
}